// Round 7
// baseline (318.598 us; speedup 1.0000x reference)
//
#include <hip/hip_runtime.h>

#define NNODES 50000
#define NEDGES 800000
#define CHUNK 3125          // edges per CSR block (256 blocks * 3125 = 800000)

typedef __attribute__((ext_vector_type(8))) short short8;
typedef __attribute__((ext_vector_type(4))) float floatx4;
typedef __attribute__((ext_vector_type(8))) _Float16 f16x8;

// async global->LDS, 16B per lane (global_load_lds_dwordx4).
// LDS dest MUST be wave-uniform base + lane*16.
__device__ __forceinline__ void async16(const void* g, void* l) {
    __builtin_amdgcn_global_load_lds(
        (const __attribute__((address_space(1))) unsigned int*)g,
        (__attribute__((address_space(3))) unsigned int*)l, 16, 0, 0);
}

__device__ __forceinline__ void split_bf16(float v, short& hi, short& lo) {
    unsigned u = __float_as_uint(v);
    unsigned hu = u & 0xffff0000u;
    hi = (short)(hu >> 16);
    float r = v - __uint_as_float(hu);
    lo = (short)(__float_as_uint(r) >> 16);
}

// ---------------- prep: weights + x split + barrier zero ----------------

#define PREP_WBLK 224
#define PREP_SBLK 6250
#define PREP_TOT  (PREP_WBLK + PREP_SBLK)

__global__ __launch_bounds__(256) void k_prep(
    const float* __restrict__ W0, short* __restrict__ W0h, short* __restrict__ W0l,
    const float* __restrict__ W1, short* __restrict__ W1h, short* __restrict__ W1l,
    const float* __restrict__ W2, short* __restrict__ W2h, short* __restrict__ W2l,
    const float* __restrict__ x, short* __restrict__ xh, short* __restrict__ xl,
    int* __restrict__ bar) {
    int b = blockIdx.x, t = threadIdx.x;
    if (b == 0 && t < 8) bar[t] = 0;       // ws is poisoned 0xAA each call
    if (b < PREP_WBLK) {
        int id = b * 256 + t;
        const float* W; short *Wh, *Wl; int K, F;
        if (id < 32768) { W = W0; Wh = W0h; Wl = W0l; K = 256; F = 128; }
        else if (id < 49152) { id -= 32768; W = W1; Wh = W1h; Wl = W1l; K = 128; F = 128; }
        else if (id < 57344) { id -= 49152; W = W2; Wh = W2h; Wl = W2l; K = 128; F = 64; }
        else return;
        int f = id / K, k = id - f * K;
        short h, l;
        split_bf16(W[(size_t)k * F + f], h, l);
        Wh[id] = h;
        Wl[id] = l;
    } else {
        // x fp32 -> hi/lo bf16, 8 elems/thread
        int i = (b - PREP_WBLK) * 256 + t;
        float4 v0 = ((const float4*)x)[i * 2];
        float4 v1 = ((const float4*)x)[i * 2 + 1];
        float va[8] = {v0.x, v0.y, v0.z, v0.w, v1.x, v1.y, v1.z, v1.w};
        short8 h8, l8;
#pragma unroll
        for (int j = 0; j < 8; j++) {
            short h, l;
            split_bf16(va[j], h, l);
            h8[j] = h; l8[j] = l;
        }
        *(short8*)&xh[i * 8] = h8;
        *(short8*)&xl[i * 8] = l8;
    }
}

// ---------------- fused CSR build (one kernel, grid spin-barrier) --------
// 256 blocks, 1 block/CU -> all co-resident; device-scope fence + atomic
// counter barrier between phases. Zero global atomics in the hot paths.

__device__ __forceinline__ void gridbar(int* bar, int idx) {
    __syncthreads();
    if (threadIdx.x == 0) {
        __threadfence();                       // release
        atomicAdd(&bar[idx], 1);
        while (atomicAdd(&bar[idx], 0) < 256) __builtin_amdgcn_s_sleep(1);
        __threadfence();                       // acquire
    }
    __syncthreads();
}

__global__ __launch_bounds__(256) void k_csr(const int* __restrict__ src,
                                             const int* __restrict__ dst,
                                             int* __restrict__ hist2d,
                                             unsigned* __restrict__ buck,
                                             int* __restrict__ rowptr,
                                             float* __restrict__ dinv,
                                             int* __restrict__ ssrc,
                                             int* bar) {
    __shared__ int h[256], ex[256], cur[256];
    __shared__ int scoff[256], stot[256];
    int t = threadIdx.x, b = blockIdx.x;
    int e0 = b * CHUNK;

    // phase 1: local coarse histogram of dst>>8
    h[t] = 0;
    __syncthreads();
#pragma unroll
    for (int k = 0; k < 13; k++) {
        int o = k * 256 + t;
        if (o < CHUNK) atomicAdd(&h[dst[e0 + o] >> 8], 1);
    }
    __syncthreads();
    hist2d[b * 256 + t] = h[t];

    gridbar(bar, 0);

    // per-bin totals + this block's exclusive prefix within each bin
    int pre = 0, tot = 0;
    for (int bb = 0; bb < 256; bb++) {
        int v = hist2d[bb * 256 + t];
        pre += (bb < b) ? v : 0;
        tot += v;
    }
    ex[t] = tot;
    __syncthreads();
    for (int o = 1; o < 256; o <<= 1) {
        int xx = (t >= o) ? ex[t - o] : 0;
        __syncthreads();
        ex[t] += xx;
        __syncthreads();
    }
    int coff = ex[t] - tot;
    scoff[t] = coff;
    stot[t] = tot;
    cur[t] = coff + pre;       // exclusive range for this block in bin t
    __syncthreads();

    // phase 2: scatter packed (src | (dst&255)<<16) — LDS cursors only
#pragma unroll
    for (int k = 0; k < 13; k++) {
        int o = k * 256 + t;
        if (o < CHUNK) {
            int s = src[e0 + o], d = dst[e0 + o];
            int p = atomicAdd(&cur[d >> 8], 1);
            buck[p] = (unsigned)s | ((unsigned)(d & 255) << 16);
        }
    }

    gridbar(bar, 1);

    // phase 3: finalize coarse bucket b: exact rowptr/dinv + ssrc scatter
    int s0 = scoff[b], S = stot[b];
    h[t] = 0;
    __syncthreads();
    for (int i = t; i < S; i += 256)
        atomicAdd(&h[(buck[s0 + i] >> 16) & 255], 1);
    __syncthreads();
    int v = h[t];
    ex[t] = v;
    __syncthreads();
    for (int o = 1; o < 256; o <<= 1) {
        int xx = (t >= o) ? ex[t - o] : 0;
        __syncthreads();
        ex[t] += xx;
        __syncthreads();
    }
    int excl = ex[t] - v;
    int n = b * 256 + t;
    if (n < NNODES) {
        rowptr[n] = s0 + excl;
        dinv[n] = rsqrtf((float)v + 1.0f);
    }
    if (b == 0 && t == 0) rowptr[NNODES] = NEDGES;
    cur[t] = excl;
    __syncthreads();
    for (int i = t; i < S; i += 256) {
        unsigned pk = buck[s0 + i];
        int dl = (pk >> 16) & 255;
        int p = atomicAdd(&cur[dl], 1);
        ssrc[s0 + p] = (int)(pk & 0xFFFFu);
    }
}

// ---------------- GEMM: g16 = fp16((A @ W) * dinv[row]) ------------------
// A hi/lo bf16 (M x K), B = W^T hi/lo (BN x K), out fp16 (M x BN).
// BM=64, BK=64, 256 thr = 4 waves; XOR-swizzled LDS (16B blocks).

template <int BN>
__global__ __launch_bounds__(256) void k_gemm2(
    const short* __restrict__ Ah, const short* __restrict__ Al,
    const short* __restrict__ Bh, const short* __restrict__ Bl,
    const float* __restrict__ dinv, _Float16* __restrict__ g16,
    int M, int K) {
    constexpr int BM = 64, BK = 64;
    constexpr int NT = BN / 16;
    __shared__ __align__(16) short sAh[BM * BK], sAl[BM * BK];
    __shared__ __align__(16) short sBh[BN * BK], sBl[BN * BK];

    const int tid = threadIdx.x, lane = tid & 63, w = tid >> 6;
    const int row0 = blockIdx.x * BM;
    const int lr = lane >> 3;
    const int lz = lane & 7;
    const int swz = (lz ^ lr) * 8;
    const int fr = lane & 15, fq = lane >> 4;

    floatx4 acc[NT] = {};

    for (int k0 = 0; k0 < K; k0 += BK) {
#pragma unroll
        for (int jj = 0; jj < 2; jj++) {
            int j = w * 2 + jj;
            int grow = row0 + j * 8 + lr;
            if (grow >= M) grow = M - 1;
            size_t go = (size_t)grow * K + k0 + swz;
            async16(&Ah[go], &sAh[j * 8 * BK + lane * 8]);
            async16(&Al[go], &sAl[j * 8 * BK + lane * 8]);
        }
#pragma unroll
        for (int jj = 0; jj < BN / 32; jj++) {
            int j = w * (BN / 32) + jj;
            size_t go = (size_t)(j * 8 + lr) * K + k0 + swz;
            async16(&Bh[go], &sBh[j * 8 * BK + lane * 8]);
            async16(&Bl[go], &sBl[j * 8 * BK + lane * 8]);
        }
        __syncthreads();

#pragma unroll
        for (int ks = 0; ks < 2; ks++) {
            int R = w * 16 + fr;
            int ca = ((ks * 4 + fq) ^ (R & 7)) * 8;
            short8 ah = *(const short8*)&sAh[R * BK + ca];
            short8 al = *(const short8*)&sAl[R * BK + ca];
#pragma unroll
            for (int nt = 0; nt < NT; nt++) {
                int n = nt * 16 + fr;
                int cb = ((ks * 4 + fq) ^ (n & 7)) * 8;
                short8 bh = *(const short8*)&sBh[n * BK + cb];
                short8 bl = *(const short8*)&sBl[n * BK + cb];
                acc[nt] = __builtin_amdgcn_mfma_f32_16x16x32_bf16(ah, bh, acc[nt], 0, 0, 0);
                acc[nt] = __builtin_amdgcn_mfma_f32_16x16x32_bf16(ah, bl, acc[nt], 0, 0, 0);
                acc[nt] = __builtin_amdgcn_mfma_f32_16x16x32_bf16(al, bh, acc[nt], 0, 0, 0);
            }
        }
        __syncthreads();
    }

#pragma unroll
    for (int rr = 0; rr < 4; rr++) {
        int grow = row0 + w * 16 + fq * 4 + rr;
        if (grow < M) {
            float dv = dinv[grow];
#pragma unroll
            for (int nt = 0; nt < NT; nt++)
                g16[(size_t)grow * BN + nt * 16 + fr] =
                    (_Float16)(acc[nt][rr] * dv);
        }
    }
}

// ---------------- Aggregation (thread-per-(node,16B-chunk), fp16) --------
// res = dinv[n]*(sum_e g[ssrc[e]] + g[n]) + b ; optional relu.

template <int F>
__global__ __launch_bounds__(256) void k_agg(const _Float16* __restrict__ g,
                                             const int* __restrict__ ssrc,
                                             const int* __restrict__ rowptr,
                                             const float* __restrict__ dinv,
                                             const float* __restrict__ bias,
                                             float* __restrict__ outf,
                                             short* __restrict__ oh,
                                             short* __restrict__ ol,
                                             int relu, int writebf) {
    constexpr int F8 = F / 8;
    int gid = blockIdx.x * 256 + threadIdx.x;
    int n = gid / F8;
    if (n >= NNODES) return;
    int c8 = gid - n * F8;
    const f16x8* gp = (const f16x8*)g;

    f16x8 sv = gp[(size_t)n * F8 + c8];       // self term
    float a0[8], a1[8], a2[8], a3[8];
#pragma unroll
    for (int j = 0; j < 8; j++) {
        a0[j] = (float)sv[j];
        a1[j] = 0.f; a2[j] = 0.f; a3[j] = 0.f;
    }
    int e0 = rowptr[n], e1 = rowptr[n + 1];
    int e = e0;
    for (; e + 4 <= e1; e += 4) {
        int s0 = ssrc[e], s1 = ssrc[e + 1], s2 = ssrc[e + 2], s3 = ssrc[e + 3];
        f16x8 v0 = gp[(size_t)s0 * F8 + c8];
        f16x8 v1 = gp[(size_t)s1 * F8 + c8];
        f16x8 v2 = gp[(size_t)s2 * F8 + c8];
        f16x8 v3 = gp[(size_t)s3 * F8 + c8];
#pragma unroll
        for (int j = 0; j < 8; j++) {
            a0[j] += (float)v0[j];
            a1[j] += (float)v1[j];
            a2[j] += (float)v2[j];
            a3[j] += (float)v3[j];
        }
    }
    for (; e < e1; e++) {
        int s = ssrc[e];
        f16x8 v = gp[(size_t)s * F8 + c8];
#pragma unroll
        for (int j = 0; j < 8; j++) a0[j] += (float)v[j];
    }
    float dv = dinv[n];
    float o[8];
#pragma unroll
    for (int j = 0; j < 8; j++) {
        float s = (a0[j] + a1[j]) + (a2[j] + a3[j]);
        o[j] = s * dv + bias[c8 * 8 + j];
        if (relu) o[j] = fmaxf(o[j], 0.f);
    }
    if (writebf) {
        short8 h8, l8;
#pragma unroll
        for (int j = 0; j < 8; j++) {
            short h, l;
            split_bf16(o[j], h, l);
            h8[j] = h; l8[j] = l;
        }
        *(short8*)&oh[(size_t)n * F + c8 * 8] = h8;
        *(short8*)&ol[(size_t)n * F + c8 * 8] = l8;
    } else {
        *(float4*)&outf[(size_t)n * F + c8 * 8] =
            make_float4(o[0], o[1], o[2], o[3]);
        *(float4*)&outf[(size_t)n * F + c8 * 8 + 4] =
            make_float4(o[4], o[5], o[6], o[7]);
    }
}

// ---------------- launch ----------------

static inline size_t align256(size_t x) { return (x + 255) & ~(size_t)255; }

extern "C" void kernel_launch(void* const* d_in, const int* in_sizes, int n_in,
                              void* d_out, int out_size, void* d_ws, size_t ws_size,
                              hipStream_t stream) {
    const float* x  = (const float*)d_in[0];
    const int*   ei = (const int*)d_in[1];
    const float* W0 = (const float*)d_in[2];
    const float* b0 = (const float*)d_in[3];
    const float* W1 = (const float*)d_in[4];
    const float* b1 = (const float*)d_in[5];
    const float* W2 = (const float*)d_in[6];
    const float* b2 = (const float*)d_in[7];
    float* out = (float*)d_out;

    const int* src = ei;
    const int* dst = ei + NEDGES;

    char* w = (char*)d_ws;
    size_t off = 0;
    float* dinv    = (float*)(w + off); off = align256(off + NNODES * 4);
    int* rowptr    = (int*)(w + off);   off = align256(off + (NNODES + 1) * 4);
    int* bar       = (int*)(w + off);   off = align256(off + 8 * 4);
    int* hist2d    = (int*)(w + off);   off = align256(off + 256 * 256 * 4);
    unsigned* buck = (unsigned*)(w + off); off = align256(off + (size_t)NEDGES * 4);
    int* ssrc      = (int*)(w + off);   off = align256(off + (size_t)NEDGES * 4);
    short* W0h     = (short*)(w + off); off = align256(off + 256 * 128 * 2);
    short* W0l     = (short*)(w + off); off = align256(off + 256 * 128 * 2);
    short* W1h     = (short*)(w + off); off = align256(off + 128 * 128 * 2);
    short* W1l     = (short*)(w + off); off = align256(off + 128 * 128 * 2);
    short* W2h     = (short*)(w + off); off = align256(off + 128 * 64 * 2);
    short* W2l     = (short*)(w + off); off = align256(off + 128 * 64 * 2);
    short* xh      = (short*)(w + off); off = align256(off + (size_t)NNODES * 256 * 2);
    short* xl      = (short*)(w + off); off = align256(off + (size_t)NNODES * 256 * 2);
    short* ph      = (short*)(w + off); off = align256(off + (size_t)NNODES * 128 * 2);
    short* pl      = (short*)(w + off); off = align256(off + (size_t)NNODES * 128 * 2);
    _Float16* g16  = (_Float16*)(w + off); off = align256(off + (size_t)NNODES * 128 * 2);

    // 1) prep: weights + x split (+ zero barrier words)
    k_prep<<<PREP_TOT, 256, 0, stream>>>(W0, W0h, W0l, W1, W1h, W1l,
                                         W2, W2h, W2l, x, xh, xl, bar);
    // 2) fused CSR build
    k_csr<<<256, 256, 0, stream>>>(src, dst, hist2d, buck, rowptr, dinv, ssrc, bar);

    const int MB = (NNODES + 63) / 64;           // 782
    const int AB128 = (NNODES * 16 + 255) / 256; // 3125
    const int AB64  = (NNODES * 8 + 255) / 256;  // 1563

    // layer 0
    k_gemm2<128><<<MB, 256, 0, stream>>>(xh, xl, W0h, W0l, dinv, g16, NNODES, 256);
    k_agg<128><<<AB128, 256, 0, stream>>>(g16, ssrc, rowptr, dinv, b0,
                                          (float*)nullptr, ph, pl, 1, 1);
    // layer 1
    k_gemm2<128><<<MB, 256, 0, stream>>>(ph, pl, W1h, W1l, dinv, g16, NNODES, 128);
    k_agg<128><<<AB128, 256, 0, stream>>>(g16, ssrc, rowptr, dinv, b1,
                                          (float*)nullptr, ph, pl, 1, 1);
    // layer 2
    k_gemm2<64><<<MB, 256, 0, stream>>>(ph, pl, W2h, W2l, dinv, g16, NNODES, 128);
    k_agg<64><<<AB64, 256, 0, stream>>>(g16, ssrc, rowptr, dinv, b2,
                                        out, (short*)nullptr, (short*)nullptr, 0, 0);
    (void)in_sizes; (void)n_in; (void)out_size; (void)ws_size;
}

// Round 8
// 279.087 us; speedup vs baseline: 1.1416x; 1.1416x over previous
//
#include <hip/hip_runtime.h>

#define NNODES 50000
#define NEDGES 800000
#define CHUNK 3125          // edges per CSR block (256 blocks * 3125 = 800000)

typedef __attribute__((ext_vector_type(8))) short short8;
typedef __attribute__((ext_vector_type(4))) float floatx4;
typedef __attribute__((ext_vector_type(8))) _Float16 f16x8;

// async global->LDS, 16B per lane (global_load_lds_dwordx4).
// LDS dest MUST be wave-uniform base + lane*16.
__device__ __forceinline__ void async16(const void* g, void* l) {
    __builtin_amdgcn_global_load_lds(
        (const __attribute__((address_space(1))) unsigned int*)g,
        (__attribute__((address_space(3))) unsigned int*)l, 16, 0, 0);
}

__device__ __forceinline__ void split_bf16(float v, short& hi, short& lo) {
    unsigned u = __float_as_uint(v);
    unsigned hu = u & 0xffff0000u;
    hi = (short)(hu >> 16);
    float r = v - __uint_as_float(hu);
    lo = (short)(__float_as_uint(r) >> 16);
}

// ------ prep: weight transpose/split + x split + coarse histogram --------

#define PREP_WBLK 224
#define PREP_SBLK 6250
#define PREP_TOT  (PREP_WBLK + PREP_SBLK + 256)

__global__ __launch_bounds__(256) void k_prep(
    const float* __restrict__ W0, short* __restrict__ W0h, short* __restrict__ W0l,
    const float* __restrict__ W1, short* __restrict__ W1h, short* __restrict__ W1l,
    const float* __restrict__ W2, short* __restrict__ W2h, short* __restrict__ W2l,
    const float* __restrict__ x, short* __restrict__ xh, short* __restrict__ xl,
    const int* __restrict__ dst, int* __restrict__ hist2d) {
    int b = blockIdx.x, t = threadIdx.x;
    if (b < PREP_WBLK) {
        // weight transpose + hi/lo split
        int id = b * 256 + t;
        const float* W; short *Wh, *Wl; int K, F;
        if (id < 32768) { W = W0; Wh = W0h; Wl = W0l; K = 256; F = 128; }
        else if (id < 49152) { id -= 32768; W = W1; Wh = W1h; Wl = W1l; K = 128; F = 128; }
        else if (id < 57344) { id -= 49152; W = W2; Wh = W2h; Wl = W2l; K = 128; F = 64; }
        else return;
        int f = id / K, k = id - f * K;
        short h, l;
        split_bf16(W[(size_t)k * F + f], h, l);
        Wh[id] = h;
        Wl[id] = l;
    } else if (b < PREP_WBLK + PREP_SBLK) {
        // x fp32 -> hi/lo bf16, 8 elems/thread
        int i = (b - PREP_WBLK) * 256 + t;
        float4 v0 = ((const float4*)x)[i * 2];
        float4 v1 = ((const float4*)x)[i * 2 + 1];
        float va[8] = {v0.x, v0.y, v0.z, v0.w, v1.x, v1.y, v1.z, v1.w};
        short8 h8, l8;
#pragma unroll
        for (int j = 0; j < 8; j++) {
            short h, l;
            split_bf16(va[j], h, l);
            h8[j] = h; l8[j] = l;
        }
        *(short8*)&xh[i * 8] = h8;
        *(short8*)&xl[i * 8] = l8;
    } else {
        // per-block coarse histogram of dst>>8 (no global atomics)
        __shared__ int h[256];
        int bb = b - PREP_WBLK - PREP_SBLK;
        h[t] = 0;
        __syncthreads();
        int e0 = bb * CHUNK;
#pragma unroll
        for (int k = 0; k < 13; k++) {
            int o = k * 256 + t;
            if (o < CHUNK) atomicAdd(&h[dst[e0 + o] >> 8], 1);
        }
        __syncthreads();
        hist2d[bb * 256 + t] = h[t];
    }
}

// P2 (self-scanning): block b re-derives the global bin layout from hist2d,
// then scatters its CHUNK edges into its deterministic per-bin ranges.
// Zero global atomics; LDS cursors only.
__global__ __launch_bounds__(256) void k_p2(const int* __restrict__ src,
                                            const int* __restrict__ dst,
                                            const int* __restrict__ hist2d,
                                            unsigned* __restrict__ buck) {
    __shared__ int ex[256], cur[256];
    int t = threadIdx.x, b = blockIdx.x;
    // column sum over blocks + my exclusive prefix within the bin
    int tot = 0, pre = 0;
    for (int bb = 0; bb < 256; bb++) {
        int v = hist2d[bb * 256 + t];
        tot += v;
        pre += (bb < b) ? v : 0;
    }
    ex[t] = tot;
    __syncthreads();
    for (int o = 1; o < 256; o <<= 1) {
        int xx = (t >= o) ? ex[t - o] : 0;
        __syncthreads();
        ex[t] += xx;
        __syncthreads();
    }
    cur[t] = (ex[t] - tot) + pre;      // bin base + my block's prefix
    __syncthreads();
    int e0 = b * CHUNK;
#pragma unroll
    for (int k = 0; k < 13; k++) {
        int o = k * 256 + t;
        if (o < CHUNK) {
            int s = src[e0 + o], d = dst[e0 + o];
            int p = atomicAdd(&cur[d >> 8], 1);   // LDS atomic only
            buck[p] = (unsigned)s | ((unsigned)(d & 255) << 16);
        }
    }
}

// P3 (self-scanning): block b finalizes coarse bin b — exact rowptr/dinv
// for nodes b*256..b*256+255 and the final ssrc scatter.
__global__ __launch_bounds__(256) void k_p3(const unsigned* __restrict__ buck,
                                            const int* __restrict__ hist2d,
                                            int* __restrict__ rowptr,
                                            float* __restrict__ dinv,
                                            int* __restrict__ ssrc) {
    __shared__ int ex[256], cur[256], h[256], sS0[1], sS[1];
    int t = threadIdx.x, b = blockIdx.x;
    int tot = 0;
    for (int bb = 0; bb < 256; bb++) tot += hist2d[bb * 256 + t];
    ex[t] = tot;
    __syncthreads();
    for (int o = 1; o < 256; o <<= 1) {
        int xx = (t >= o) ? ex[t - o] : 0;
        __syncthreads();
        ex[t] += xx;
        __syncthreads();
    }
    if (t == b) { sS0[0] = ex[t] - tot; sS[0] = tot; }
    h[t] = 0;
    __syncthreads();
    int s0 = sS0[0], S = sS[0];
    for (int i = t; i < S; i += 256)
        atomicAdd(&h[(buck[s0 + i] >> 16) & 255], 1);
    __syncthreads();
    int v = h[t];
    ex[t] = v;
    __syncthreads();
    for (int o = 1; o < 256; o <<= 1) {
        int xx = (t >= o) ? ex[t - o] : 0;
        __syncthreads();
        ex[t] += xx;
        __syncthreads();
    }
    int excl = ex[t] - v;
    int n = b * 256 + t;
    if (n < NNODES) {
        rowptr[n] = s0 + excl;
        dinv[n] = rsqrtf((float)v + 1.0f);
    }
    if (b == 0 && t == 0) rowptr[NNODES] = NEDGES;
    cur[t] = excl;
    __syncthreads();
    for (int i = t; i < S; i += 256) {
        unsigned pk = buck[s0 + i];
        int dl = (pk >> 16) & 255;
        int p = atomicAdd(&cur[dl], 1);
        ssrc[s0 + p] = (int)(pk & 0xFFFFu);
    }
}

// ---------------- GEMM: g16 = fp16((A @ W) * dinv[row]) ------------------
// A hi/lo bf16 (M x K), B = W^T hi/lo (BN x K), out fp16 (M x BN).
// BM=64, BK=64, 256 thr = 4 waves; XOR-swizzled LDS (16B blocks).

template <int BN>
__global__ __launch_bounds__(256) void k_gemm2(
    const short* __restrict__ Ah, const short* __restrict__ Al,
    const short* __restrict__ Bh, const short* __restrict__ Bl,
    const float* __restrict__ dinv, _Float16* __restrict__ g16,
    int M, int K) {
    constexpr int BM = 64, BK = 64;
    constexpr int NT = BN / 16;
    __shared__ __align__(16) short sAh[BM * BK], sAl[BM * BK];
    __shared__ __align__(16) short sBh[BN * BK], sBl[BN * BK];

    const int tid = threadIdx.x, lane = tid & 63, w = tid >> 6;
    const int row0 = blockIdx.x * BM;
    const int lr = lane >> 3;
    const int lz = lane & 7;
    const int swz = (lz ^ lr) * 8;
    const int fr = lane & 15, fq = lane >> 4;

    floatx4 acc[NT] = {};

    for (int k0 = 0; k0 < K; k0 += BK) {
#pragma unroll
        for (int jj = 0; jj < 2; jj++) {
            int j = w * 2 + jj;
            int grow = row0 + j * 8 + lr;
            if (grow >= M) grow = M - 1;
            size_t go = (size_t)grow * K + k0 + swz;
            async16(&Ah[go], &sAh[j * 8 * BK + lane * 8]);
            async16(&Al[go], &sAl[j * 8 * BK + lane * 8]);
        }
#pragma unroll
        for (int jj = 0; jj < BN / 32; jj++) {
            int j = w * (BN / 32) + jj;
            size_t go = (size_t)(j * 8 + lr) * K + k0 + swz;
            async16(&Bh[go], &sBh[j * 8 * BK + lane * 8]);
            async16(&Bl[go], &sBl[j * 8 * BK + lane * 8]);
        }
        __syncthreads();

#pragma unroll
        for (int ks = 0; ks < 2; ks++) {
            int R = w * 16 + fr;
            int ca = ((ks * 4 + fq) ^ (R & 7)) * 8;
            short8 ah = *(const short8*)&sAh[R * BK + ca];
            short8 al = *(const short8*)&sAl[R * BK + ca];
#pragma unroll
            for (int nt = 0; nt < NT; nt++) {
                int n = nt * 16 + fr;
                int cb = ((ks * 4 + fq) ^ (n & 7)) * 8;
                short8 bh = *(const short8*)&sBh[n * BK + cb];
                short8 bl = *(const short8*)&sBl[n * BK + cb];
                acc[nt] = __builtin_amdgcn_mfma_f32_16x16x32_bf16(ah, bh, acc[nt], 0, 0, 0);
                acc[nt] = __builtin_amdgcn_mfma_f32_16x16x32_bf16(ah, bl, acc[nt], 0, 0, 0);
                acc[nt] = __builtin_amdgcn_mfma_f32_16x16x32_bf16(al, bh, acc[nt], 0, 0, 0);
            }
        }
        __syncthreads();
    }

#pragma unroll
    for (int rr = 0; rr < 4; rr++) {
        int grow = row0 + w * 16 + fq * 4 + rr;
        if (grow < M) {
            float dv = dinv[grow];
#pragma unroll
            for (int nt = 0; nt < NT; nt++)
                g16[(size_t)grow * BN + nt * 16 + fr] =
                    (_Float16)(acc[nt][rr] * dv);
        }
    }
}

// ---------------- Aggregation (thread-per-(node,16B-chunk), fp16) --------
// res = dinv[n]*(sum_e g[ssrc[e]] + g[n]) + b ; optional relu.

template <int F>
__global__ __launch_bounds__(256) void k_agg(const _Float16* __restrict__ g,
                                             const int* __restrict__ ssrc,
                                             const int* __restrict__ rowptr,
                                             const float* __restrict__ dinv,
                                             const float* __restrict__ bias,
                                             float* __restrict__ outf,
                                             short* __restrict__ oh,
                                             short* __restrict__ ol,
                                             int relu, int writebf) {
    constexpr int F8 = F / 8;
    int gid = blockIdx.x * 256 + threadIdx.x;
    int n = gid / F8;
    if (n >= NNODES) return;
    int c8 = gid - n * F8;
    const f16x8* gp = (const f16x8*)g;

    f16x8 sv = gp[(size_t)n * F8 + c8];       // self term
    float a0[8], a1[8], a2[8], a3[8];
#pragma unroll
    for (int j = 0; j < 8; j++) {
        a0[j] = (float)sv[j];
        a1[j] = 0.f; a2[j] = 0.f; a3[j] = 0.f;
    }
    int e0 = rowptr[n], e1 = rowptr[n + 1];
    int e = e0;
    for (; e + 4 <= e1; e += 4) {
        int s0 = ssrc[e], s1 = ssrc[e + 1], s2 = ssrc[e + 2], s3 = ssrc[e + 3];
        f16x8 v0 = gp[(size_t)s0 * F8 + c8];
        f16x8 v1 = gp[(size_t)s1 * F8 + c8];
        f16x8 v2 = gp[(size_t)s2 * F8 + c8];
        f16x8 v3 = gp[(size_t)s3 * F8 + c8];
#pragma unroll
        for (int j = 0; j < 8; j++) {
            a0[j] += (float)v0[j];
            a1[j] += (float)v1[j];
            a2[j] += (float)v2[j];
            a3[j] += (float)v3[j];
        }
    }
    for (; e < e1; e++) {
        int s = ssrc[e];
        f16x8 v = gp[(size_t)s * F8 + c8];
#pragma unroll
        for (int j = 0; j < 8; j++) a0[j] += (float)v[j];
    }
    float dv = dinv[n];
    float o[8];
#pragma unroll
    for (int j = 0; j < 8; j++) {
        float s = (a0[j] + a1[j]) + (a2[j] + a3[j]);
        o[j] = s * dv + bias[c8 * 8 + j];
        if (relu) o[j] = fmaxf(o[j], 0.f);
    }
    if (writebf) {
        short8 h8, l8;
#pragma unroll
        for (int j = 0; j < 8; j++) {
            short h, l;
            split_bf16(o[j], h, l);
            h8[j] = h; l8[j] = l;
        }
        *(short8*)&oh[(size_t)n * F + c8 * 8] = h8;
        *(short8*)&ol[(size_t)n * F + c8 * 8] = l8;
    } else {
        *(float4*)&outf[(size_t)n * F + c8 * 8] =
            make_float4(o[0], o[1], o[2], o[3]);
        *(float4*)&outf[(size_t)n * F + c8 * 8 + 4] =
            make_float4(o[4], o[5], o[6], o[7]);
    }
}

// ---------------- launch ----------------

static inline size_t align256(size_t x) { return (x + 255) & ~(size_t)255; }

extern "C" void kernel_launch(void* const* d_in, const int* in_sizes, int n_in,
                              void* d_out, int out_size, void* d_ws, size_t ws_size,
                              hipStream_t stream) {
    const float* x  = (const float*)d_in[0];
    const int*   ei = (const int*)d_in[1];
    const float* W0 = (const float*)d_in[2];
    const float* b0 = (const float*)d_in[3];
    const float* W1 = (const float*)d_in[4];
    const float* b1 = (const float*)d_in[5];
    const float* W2 = (const float*)d_in[6];
    const float* b2 = (const float*)d_in[7];
    float* out = (float*)d_out;

    const int* src = ei;
    const int* dst = ei + NEDGES;

    char* w = (char*)d_ws;
    size_t off = 0;
    float* dinv    = (float*)(w + off); off = align256(off + NNODES * 4);
    int* rowptr    = (int*)(w + off);   off = align256(off + (NNODES + 1) * 4);
    int* hist2d    = (int*)(w + off);   off = align256(off + 256 * 256 * 4);
    unsigned* buck = (unsigned*)(w + off); off = align256(off + (size_t)NEDGES * 4);
    int* ssrc      = (int*)(w + off);   off = align256(off + (size_t)NEDGES * 4);
    short* W0h     = (short*)(w + off); off = align256(off + 256 * 128 * 2);
    short* W0l     = (short*)(w + off); off = align256(off + 256 * 128 * 2);
    short* W1h     = (short*)(w + off); off = align256(off + 128 * 128 * 2);
    short* W1l     = (short*)(w + off); off = align256(off + 128 * 128 * 2);
    short* W2h     = (short*)(w + off); off = align256(off + 128 * 64 * 2);
    short* W2l     = (short*)(w + off); off = align256(off + 128 * 64 * 2);
    short* xh      = (short*)(w + off); off = align256(off + (size_t)NNODES * 256 * 2);
    short* xl      = (short*)(w + off); off = align256(off + (size_t)NNODES * 256 * 2);
    short* ph      = (short*)(w + off); off = align256(off + (size_t)NNODES * 128 * 2);
    short* pl      = (short*)(w + off); off = align256(off + (size_t)NNODES * 128 * 2);
    _Float16* g16  = (_Float16*)(w + off); off = align256(off + (size_t)NNODES * 128 * 2);

    // 1) prep: weights + x split + coarse histogram
    k_prep<<<PREP_TOT, 256, 0, stream>>>(W0, W0h, W0l, W1, W1h, W1l,
                                         W2, W2h, W2l, x, xh, xl, dst, hist2d);
    // 2) coarse scatter (self-scanning, no global atomics)
    k_p2<<<256, 256, 0, stream>>>(src, dst, hist2d, buck);
    // 3) per-bucket finalize: rowptr/dinv/ssrc
    k_p3<<<256, 256, 0, stream>>>(buck, hist2d, rowptr, dinv, ssrc);

    const int MB = (NNODES + 63) / 64;           // 782
    const int AB128 = (NNODES * 16 + 255) / 256; // 3125
    const int AB64  = (NNODES * 8 + 255) / 256;  // 1563

    // layer 0
    k_gemm2<128><<<MB, 256, 0, stream>>>(xh, xl, W0h, W0l, dinv, g16, NNODES, 256);
    k_agg<128><<<AB128, 256, 0, stream>>>(g16, ssrc, rowptr, dinv, b0,
                                          (float*)nullptr, ph, pl, 1, 1);
    // layer 1
    k_gemm2<128><<<MB, 256, 0, stream>>>(ph, pl, W1h, W1l, dinv, g16, NNODES, 128);
    k_agg<128><<<AB128, 256, 0, stream>>>(g16, ssrc, rowptr, dinv, b1,
                                          (float*)nullptr, ph, pl, 1, 1);
    // layer 2
    k_gemm2<64><<<MB, 256, 0, stream>>>(ph, pl, W2h, W2l, dinv, g16, NNODES, 128);
    k_agg<64><<<AB64, 256, 0, stream>>>(g16, ssrc, rowptr, dinv, b2,
                                        out, (short*)nullptr, (short*)nullptr, 0, 0);
    (void)in_sizes; (void)n_in; (void)out_size; (void)ws_size;
}

// Round 9
// 267.896 us; speedup vs baseline: 1.1893x; 1.0418x over previous
//
#include <hip/hip_runtime.h>

#define NNODES 50000
#define NEDGES 800000
#define CHUNK 3125          // edges per CSR block (256 blocks * 3125 = 800000)

typedef __attribute__((ext_vector_type(8))) short short8;
typedef __attribute__((ext_vector_type(4))) float floatx4;
typedef __attribute__((ext_vector_type(8))) _Float16 f16x8;

// async global->LDS, 16B per lane (global_load_lds_dwordx4).
// LDS dest MUST be wave-uniform base + lane*16.
__device__ __forceinline__ void async16(const void* g, void* l) {
    __builtin_amdgcn_global_load_lds(
        (const __attribute__((address_space(1))) unsigned int*)g,
        (__attribute__((address_space(3))) unsigned int*)l, 16, 0, 0);
}

__device__ __forceinline__ void split_bf16(float v, short& hi, short& lo) {
    unsigned u = __float_as_uint(v);
    unsigned hu = u & 0xffff0000u;
    hi = (short)(hu >> 16);
    float r = v - __uint_as_float(hu);
    lo = (short)(__float_as_uint(r) >> 16);
}

// ------ prep: weight transpose/split + coarse histogram ------------------

#define PREP_WBLK 224
#define PREP_TOT  (PREP_WBLK + 256)

__global__ __launch_bounds__(256) void k_prep(
    const float* __restrict__ W0, short* __restrict__ W0h, short* __restrict__ W0l,
    const float* __restrict__ W1, short* __restrict__ W1h, short* __restrict__ W1l,
    const float* __restrict__ W2, short* __restrict__ W2h, short* __restrict__ W2l,
    const int* __restrict__ dst, int* __restrict__ hist2d) {
    int b = blockIdx.x, t = threadIdx.x;
    if (b < PREP_WBLK) {
        int id = b * 256 + t;
        const float* W; short *Wh, *Wl; int K, F;
        if (id < 32768) { W = W0; Wh = W0h; Wl = W0l; K = 256; F = 128; }
        else if (id < 49152) { id -= 32768; W = W1; Wh = W1h; Wl = W1l; K = 128; F = 128; }
        else if (id < 57344) { id -= 49152; W = W2; Wh = W2h; Wl = W2l; K = 128; F = 64; }
        else return;
        int f = id / K, k = id - f * K;
        short h, l;
        split_bf16(W[(size_t)k * F + f], h, l);
        Wh[id] = h;
        Wl[id] = l;
    } else {
        // per-block coarse histogram of dst>>8 (no global atomics)
        __shared__ int h[256];
        int bb = b - PREP_WBLK;
        h[t] = 0;
        __syncthreads();
        int e0 = bb * CHUNK;
#pragma unroll
        for (int k = 0; k < 13; k++) {
            int o = k * 256 + t;
            if (o < CHUNK) atomicAdd(&h[dst[e0 + o] >> 8], 1);
        }
        __syncthreads();
        hist2d[bb * 256 + t] = h[t];
    }
}

// P2 (self-scanning): deterministic coarse scatter, LDS cursors only.
__global__ __launch_bounds__(256) void k_p2(const int* __restrict__ src,
                                            const int* __restrict__ dst,
                                            const int* __restrict__ hist2d,
                                            unsigned* __restrict__ buck) {
    __shared__ int ex[256], cur[256];
    int t = threadIdx.x, b = blockIdx.x;
    int tot = 0, pre = 0;
    for (int bb = 0; bb < 256; bb++) {
        int v = hist2d[bb * 256 + t];
        tot += v;
        pre += (bb < b) ? v : 0;
    }
    ex[t] = tot;
    __syncthreads();
    for (int o = 1; o < 256; o <<= 1) {
        int xx = (t >= o) ? ex[t - o] : 0;
        __syncthreads();
        ex[t] += xx;
        __syncthreads();
    }
    cur[t] = (ex[t] - tot) + pre;
    __syncthreads();
    int e0 = b * CHUNK;
#pragma unroll
    for (int k = 0; k < 13; k++) {
        int o = k * 256 + t;
        if (o < CHUNK) {
            int s = src[e0 + o], d = dst[e0 + o];
            int p = atomicAdd(&cur[d >> 8], 1);   // LDS atomic only
            buck[p] = (unsigned)s | ((unsigned)(d & 255) << 16);
        }
    }
}

// P3 (self-scanning): finalize coarse bin b -> rowptr/dinv/ssrc.
__global__ __launch_bounds__(256) void k_p3(const unsigned* __restrict__ buck,
                                            const int* __restrict__ hist2d,
                                            int* __restrict__ rowptr,
                                            float* __restrict__ dinv,
                                            int* __restrict__ ssrc) {
    __shared__ int ex[256], cur[256], h[256], sS0[1], sS[1];
    int t = threadIdx.x, b = blockIdx.x;
    int tot = 0;
    for (int bb = 0; bb < 256; bb++) tot += hist2d[bb * 256 + t];
    ex[t] = tot;
    __syncthreads();
    for (int o = 1; o < 256; o <<= 1) {
        int xx = (t >= o) ? ex[t - o] : 0;
        __syncthreads();
        ex[t] += xx;
        __syncthreads();
    }
    if (t == b) { sS0[0] = ex[t] - tot; sS[0] = tot; }
    h[t] = 0;
    __syncthreads();
    int s0 = sS0[0], S = sS[0];
    for (int i = t; i < S; i += 256)
        atomicAdd(&h[(buck[s0 + i] >> 16) & 255], 1);
    __syncthreads();
    int v = h[t];
    ex[t] = v;
    __syncthreads();
    for (int o = 1; o < 256; o <<= 1) {
        int xx = (t >= o) ? ex[t - o] : 0;
        __syncthreads();
        ex[t] += xx;
        __syncthreads();
    }
    int excl = ex[t] - v;
    int n = b * 256 + t;
    if (n < NNODES) {
        rowptr[n] = s0 + excl;
        dinv[n] = rsqrtf((float)v + 1.0f);
    }
    if (b == 0 && t == 0) rowptr[NNODES] = NEDGES;
    cur[t] = excl;
    __syncthreads();
    for (int i = t; i < S; i += 256) {
        unsigned pk = buck[s0 + i];
        int dl = (pk >> 16) & 255;
        int p = atomicAdd(&cur[dl], 1);
        ssrc[s0 + p] = (int)(pk & 0xFFFFu);
    }
}

// ------ gemm0: g16 = fp16((x @ W0) * dinv[row]) --------------------------
// Reads x fp32 directly; in-register hi/lo split; swizzled per-lane
// ds_write_b128 for A; async16 staging for B. BM=64, BK=64, K=256, BN=128.

__global__ __launch_bounds__(256) void k_gemm0(
    const float* __restrict__ x, const short* __restrict__ Bh,
    const short* __restrict__ Bl, const float* __restrict__ dinv,
    _Float16* __restrict__ g16) {
    __shared__ __align__(16) short sAh[64 * 64], sAl[64 * 64];
    __shared__ __align__(16) short sBh[128 * 64], sBl[128 * 64];
    const int t = threadIdx.x, lane = t & 63, w = t >> 6;
    const int row0 = blockIdx.x * 64;
    const int lr = lane >> 3, lz = lane & 7;
    const int swz = (lz ^ lr) * 8;
    const int fr = lane & 15, fq = lane >> 4;
    floatx4 acc[8] = {};
    const int ar = t >> 2, ac = t & 3;
    int garow = row0 + ar;
    if (garow >= NNODES) garow = NNODES - 1;
    const float* xrow = x + (size_t)garow * 256 + ac * 16;

    for (int k0 = 0; k0 < 256; k0 += 64) {
        // A: 16 fp32 -> bf16 hi/lo -> swizzled LDS
        const float4* xp = (const float4*)(xrow + k0);
        float4 f0 = xp[0], f1 = xp[1], f2 = xp[2], f3 = xp[3];
        float va[16] = {f0.x, f0.y, f0.z, f0.w, f1.x, f1.y, f1.z, f1.w,
                        f2.x, f2.y, f2.z, f2.w, f3.x, f3.y, f3.z, f3.w};
        short8 h0, h1, l0, l1;
#pragma unroll
        for (int j = 0; j < 8; j++) {
            short h, l;
            split_bf16(va[j], h, l);     h0[j] = h; l0[j] = l;
            split_bf16(va[8 + j], h, l); h1[j] = h; l1[j] = l;
        }
        int c0 = ac * 2;
        *(short8*)&sAh[ar * 64 + ((c0 ^ (ar & 7)) * 8)] = h0;
        *(short8*)&sAh[ar * 64 + (((c0 + 1) ^ (ar & 7)) * 8)] = h1;
        *(short8*)&sAl[ar * 64 + ((c0 ^ (ar & 7)) * 8)] = l0;
        *(short8*)&sAl[ar * 64 + (((c0 + 1) ^ (ar & 7)) * 8)] = l1;
        // B staging
#pragma unroll
        for (int jj = 0; jj < 4; jj++) {
            int j = w * 4 + jj;
            size_t go = (size_t)(j * 8 + lr) * 256 + k0 + swz;
            async16(&Bh[go], &sBh[j * 512 + lane * 8]);
            async16(&Bl[go], &sBl[j * 512 + lane * 8]);
        }
        __syncthreads();
#pragma unroll
        for (int ks = 0; ks < 2; ks++) {
            int R = w * 16 + fr;
            int ca = ((ks * 4 + fq) ^ (R & 7)) * 8;
            short8 ah = *(const short8*)&sAh[R * 64 + ca];
            short8 al = *(const short8*)&sAl[R * 64 + ca];
#pragma unroll
            for (int nt = 0; nt < 8; nt++) {
                int n = nt * 16 + fr;
                int cb = ((ks * 4 + fq) ^ (n & 7)) * 8;
                short8 bh = *(const short8*)&sBh[n * 64 + cb];
                short8 bl = *(const short8*)&sBl[n * 64 + cb];
                acc[nt] = __builtin_amdgcn_mfma_f32_16x16x32_bf16(ah, bh, acc[nt], 0, 0, 0);
                acc[nt] = __builtin_amdgcn_mfma_f32_16x16x32_bf16(ah, bl, acc[nt], 0, 0, 0);
                acc[nt] = __builtin_amdgcn_mfma_f32_16x16x32_bf16(al, bh, acc[nt], 0, 0, 0);
            }
        }
        __syncthreads();
    }
#pragma unroll
    for (int rr = 0; rr < 4; rr++) {
        int grow = row0 + w * 16 + fq * 4 + rr;
        if (grow < NNODES) {
            float dv = dinv[grow];
#pragma unroll
            for (int nt = 0; nt < 8; nt++)
                g16[(size_t)grow * 128 + nt * 16 + fr] =
                    (_Float16)(acc[nt][rr] * dv);
        }
    }
}

// ------ fused agg+gemm: gout = fp16((relu(agg(gin)+b) @ W) * dinv) -------
// Phase 1: each block gathers/activates its 64 h-rows (thread =(row,16B
// chunk)) and writes bf16 hi/lo straight into the swizzled A-LDS (full
// K=128). Phase 2: BK=32 B-staging + MFMA. No global h round-trip.

template <int BN>
__global__ __launch_bounds__(256) void k_fg(
    const _Float16* __restrict__ gin, const int* __restrict__ ssrc,
    const int* __restrict__ rowptr, const float* __restrict__ dinv,
    const float* __restrict__ bias, const short* __restrict__ Bh,
    const short* __restrict__ Bl, _Float16* __restrict__ gout) {
    constexpr int NT = BN / 16;
    __shared__ __align__(16) short sAh[64 * 128], sAl[64 * 128];
    __shared__ __align__(16) short sBh[BN * 32], sBl[BN * 32];
    const int t = threadIdx.x, lane = t & 63, w = t >> 6;
    const int row0 = blockIdx.x * 64;
    const int fr = lane & 15, fq = lane >> 4;
    const f16x8* gp = (const f16x8*)gin;

    // ---- phase 1: gather h rows ----
    const int cc = t & 15;
#pragma unroll
    for (int pass = 0; pass < 4; pass++) {
        int r = pass * 16 + (t >> 4);
        int grow = row0 + r;
        if (grow >= NNODES) grow = NNODES - 1;
        f16x8 sv = gp[(size_t)grow * 16 + cc];
        float a0[8], a1[8], a2[8], a3[8];
#pragma unroll
        for (int j = 0; j < 8; j++) {
            a0[j] = (float)sv[j];
            a1[j] = 0.f; a2[j] = 0.f; a3[j] = 0.f;
        }
        int e0 = rowptr[grow], e1 = rowptr[grow + 1];
        int e = e0;
        for (; e + 4 <= e1; e += 4) {
            int s0 = ssrc[e], s1 = ssrc[e + 1], s2 = ssrc[e + 2], s3 = ssrc[e + 3];
            f16x8 v0 = gp[(size_t)s0 * 16 + cc];
            f16x8 v1 = gp[(size_t)s1 * 16 + cc];
            f16x8 v2 = gp[(size_t)s2 * 16 + cc];
            f16x8 v3 = gp[(size_t)s3 * 16 + cc];
#pragma unroll
            for (int j = 0; j < 8; j++) {
                a0[j] += (float)v0[j];
                a1[j] += (float)v1[j];
                a2[j] += (float)v2[j];
                a3[j] += (float)v3[j];
            }
        }
        for (; e < e1; e++) {
            int s = ssrc[e];
            f16x8 v = gp[(size_t)s * 16 + cc];
#pragma unroll
            for (int j = 0; j < 8; j++) a0[j] += (float)v[j];
        }
        float dv = dinv[grow];
        short8 h8, l8;
#pragma unroll
        for (int j = 0; j < 8; j++) {
            float s = (a0[j] + a1[j]) + (a2[j] + a3[j]);
            float o = fmaxf(s * dv + bias[cc * 8 + j], 0.f);
            short hh, ll;
            split_bf16(o, hh, ll);
            h8[j] = hh; l8[j] = ll;
        }
        int slot = ((cc & 7) ^ (r & 7)) + (cc >> 3) * 8;
        *(short8*)&sAh[r * 128 + slot * 8] = h8;
        *(short8*)&sAl[r * 128 + slot * 8] = l8;
    }
    __syncthreads();

    // ---- phase 2: BK=32 B staging + MFMA ----
    floatx4 acc[NT] = {};
    const int lrB = lane >> 2, lzB = lane & 3;
    for (int q = 0; q < 4; q++) {
#pragma unroll
        for (int jj = 0; jj < BN / 64; jj++) {
            int j = w * (BN / 64) + jj;
            int brow = j * 16 + lrB;
            size_t go = (size_t)brow * 128 + q * 32 + ((lzB ^ (lrB & 3)) * 8);
            async16(&Bh[go], &sBh[j * 512 + lane * 8]);
            async16(&Bl[go], &sBl[j * 512 + lane * 8]);
        }
        __syncthreads();
        int R = w * 16 + fr;
        int c = q * 4 + fq;
        int slotA = ((c & 7) ^ (R & 7)) + (c >> 3) * 8;
        short8 ah = *(const short8*)&sAh[R * 128 + slotA * 8];
        short8 al = *(const short8*)&sAl[R * 128 + slotA * 8];
#pragma unroll
        for (int nt = 0; nt < NT; nt++) {
            int n = nt * 16 + fr;
            short8 bh = *(const short8*)&sBh[n * 32 + ((fq ^ (n & 3)) * 8)];
            short8 bl = *(const short8*)&sBl[n * 32 + ((fq ^ (n & 3)) * 8)];
            acc[nt] = __builtin_amdgcn_mfma_f32_16x16x32_bf16(ah, bh, acc[nt], 0, 0, 0);
            acc[nt] = __builtin_amdgcn_mfma_f32_16x16x32_bf16(ah, bl, acc[nt], 0, 0, 0);
            acc[nt] = __builtin_amdgcn_mfma_f32_16x16x32_bf16(al, bh, acc[nt], 0, 0, 0);
        }
        __syncthreads();
    }

#pragma unroll
    for (int rr = 0; rr < 4; rr++) {
        int grow = row0 + w * 16 + fq * 4 + rr;
        if (grow < NNODES) {
            float dv = dinv[grow];
#pragma unroll
            for (int nt = 0; nt < NT; nt++)
                gout[(size_t)grow * BN + nt * 16 + fr] =
                    (_Float16)(acc[nt][rr] * dv);
        }
    }
}

// ------ final aggregation (thread-per-(node,16B-chunk), fp32 out) --------

template <int F>
__global__ __launch_bounds__(256) void k_agg(const _Float16* __restrict__ g,
                                             const int* __restrict__ ssrc,
                                             const int* __restrict__ rowptr,
                                             const float* __restrict__ dinv,
                                             const float* __restrict__ bias,
                                             float* __restrict__ outf) {
    constexpr int F8 = F / 8;
    int gid = blockIdx.x * 256 + threadIdx.x;
    int n = gid / F8;
    if (n >= NNODES) return;
    int c8 = gid - n * F8;
    const f16x8* gp = (const f16x8*)g;

    f16x8 sv = gp[(size_t)n * F8 + c8];
    float a0[8], a1[8], a2[8], a3[8];
#pragma unroll
    for (int j = 0; j < 8; j++) {
        a0[j] = (float)sv[j];
        a1[j] = 0.f; a2[j] = 0.f; a3[j] = 0.f;
    }
    int e0 = rowptr[n], e1 = rowptr[n + 1];
    int e = e0;
    for (; e + 4 <= e1; e += 4) {
        int s0 = ssrc[e], s1 = ssrc[e + 1], s2 = ssrc[e + 2], s3 = ssrc[e + 3];
        f16x8 v0 = gp[(size_t)s0 * F8 + c8];
        f16x8 v1 = gp[(size_t)s1 * F8 + c8];
        f16x8 v2 = gp[(size_t)s2 * F8 + c8];
        f16x8 v3 = gp[(size_t)s3 * F8 + c8];
#pragma unroll
        for (int j = 0; j < 8; j++) {
            a0[j] += (float)v0[j];
            a1[j] += (float)v1[j];
            a2[j] += (float)v2[j];
            a3[j] += (float)v3[j];
        }
    }
    for (; e < e1; e++) {
        int s = ssrc[e];
        f16x8 v = gp[(size_t)s * F8 + c8];
#pragma unroll
        for (int j = 0; j < 8; j++) a0[j] += (float)v[j];
    }
    float dv = dinv[n];
    float o[8];
#pragma unroll
    for (int j = 0; j < 8; j++) {
        float s = (a0[j] + a1[j]) + (a2[j] + a3[j]);
        o[j] = s * dv + bias[c8 * 8 + j];
    }
    *(float4*)&outf[(size_t)n * F + c8 * 8] = make_float4(o[0], o[1], o[2], o[3]);
    *(float4*)&outf[(size_t)n * F + c8 * 8 + 4] = make_float4(o[4], o[5], o[6], o[7]);
}

// ---------------- launch ----------------

static inline size_t align256(size_t x) { return (x + 255) & ~(size_t)255; }

extern "C" void kernel_launch(void* const* d_in, const int* in_sizes, int n_in,
                              void* d_out, int out_size, void* d_ws, size_t ws_size,
                              hipStream_t stream) {
    const float* x  = (const float*)d_in[0];
    const int*   ei = (const int*)d_in[1];
    const float* W0 = (const float*)d_in[2];
    const float* b0 = (const float*)d_in[3];
    const float* W1 = (const float*)d_in[4];
    const float* b1 = (const float*)d_in[5];
    const float* W2 = (const float*)d_in[6];
    const float* b2 = (const float*)d_in[7];
    float* out = (float*)d_out;

    const int* src = ei;
    const int* dst = ei + NEDGES;

    char* w = (char*)d_ws;
    size_t off = 0;
    float* dinv    = (float*)(w + off); off = align256(off + NNODES * 4);
    int* rowptr    = (int*)(w + off);   off = align256(off + (NNODES + 1) * 4);
    int* hist2d    = (int*)(w + off);   off = align256(off + 256 * 256 * 4);
    unsigned* buck = (unsigned*)(w + off); off = align256(off + (size_t)NEDGES * 4);
    int* ssrc      = (int*)(w + off);   off = align256(off + (size_t)NEDGES * 4);
    short* W0h     = (short*)(w + off); off = align256(off + 256 * 128 * 2);
    short* W0l     = (short*)(w + off); off = align256(off + 256 * 128 * 2);
    short* W1h     = (short*)(w + off); off = align256(off + 128 * 128 * 2);
    short* W1l     = (short*)(w + off); off = align256(off + 128 * 128 * 2);
    short* W2h     = (short*)(w + off); off = align256(off + 128 * 64 * 2);
    short* W2l     = (short*)(w + off); off = align256(off + 128 * 64 * 2);
    _Float16* g16a = (_Float16*)(w + off); off = align256(off + (size_t)NNODES * 128 * 2);
    _Float16* g16b = (_Float16*)(w + off); off = align256(off + (size_t)NNODES * 128 * 2);
    _Float16* g16c = (_Float16*)(w + off); off = align256(off + (size_t)NNODES * 64 * 2);

    const int MB = (NNODES + 63) / 64;           // 782
    const int AB64 = (NNODES * 8 + 255) / 256;   // 1563

    // 1) prep: weights + coarse histogram
    k_prep<<<PREP_TOT, 256, 0, stream>>>(W0, W0h, W0l, W1, W1h, W1l,
                                         W2, W2h, W2l, dst, hist2d);
    // 2) coarse scatter
    k_p2<<<256, 256, 0, stream>>>(src, dst, hist2d, buck);
    // 3) finalize: rowptr/dinv/ssrc
    k_p3<<<256, 256, 0, stream>>>(buck, hist2d, rowptr, dinv, ssrc);
    // 4) layer-0 gemm (direct x)
    k_gemm0<<<MB, 256, 0, stream>>>(x, W0h, W0l, dinv, g16a);
    // 5) fused agg0+gemm1
    k_fg<128><<<MB, 256, 0, stream>>>(g16a, ssrc, rowptr, dinv, b0, W1h, W1l, g16b);
    // 6) fused agg1+gemm2
    k_fg<64><<<MB, 256, 0, stream>>>(g16b, ssrc, rowptr, dinv, b1, W2h, W2l, g16c);
    // 7) final aggregation -> fp32 out
    k_agg<64><<<AB64, 256, 0, stream>>>(g16c, ssrc, rowptr, dinv, b2, out);
    (void)in_sizes; (void)n_in; (void)out_size; (void)ws_size;
}